// Round 1
// baseline (611.876 us; speedup 1.0000x reference)
//
#include <hip/hip_runtime.h>

#define T       512
#define DIN     32
#define HCELLS  64
#define NB      16      // batch elems per block (MFMA N dim)
#define TB      256     // 4 waves: each wave owns a 16-hidden slice of BOTH layers
#define GRID    64      // 1024 / NB

typedef _Float16 half8  __attribute__((ext_vector_type(8)));
typedef _Float16 half4v __attribute__((ext_vector_type(4)));
typedef float    float4v __attribute__((ext_vector_type(4)));

// LDS fp16 double-buffered h state only (x no longer staged through LDS).
#define STRH    72      // h rows: 64 + 8 pad (halfs)
#define H0H_OFF 0                       // [2][16][STRH]
#define H1H_OFF (2*16*STRH)
#define SB_HALFS (H1H_OFF + 2*16*STRH)

#define LOG2E   1.44269504f
#define SLOG2E  2.88539008f     // 2*log2(e); cell state kept as cs = SLOG2E * c

__device__ __forceinline__ int hidx(int p, int n, int k) { return (p * 16 + n) * STRH + k; }

__device__ __forceinline__ void cvt8(const float* v, half8& hi) {
    #pragma unroll
    for (int e = 0; e < 8; ++e) hi[e] = (_Float16)v[e];
}

// Scaled-domain LSTM cell update (gate scales folded into weights):
//   acc[0]=-log2e*zi, acc[1]=-log2e*zf, acc[2]=2log2e*zg, acc[3]=-log2e*zo ; cs = 2log2e*c
__device__ __forceinline__ void cell_update(const float4v acc[4], float* cs,
                                            half4v& hh, float* hout)
{
    #pragma unroll
    for (int r = 0; r < 4; ++r) {
        float ei = __builtin_amdgcn_exp2f(acc[0][r]);   // e^{-zi}
        float ef = __builtin_amdgcn_exp2f(acc[1][r]);   // e^{-zf}
        float G2 = __builtin_amdgcn_exp2f(acc[2][r]);   // e^{2 zg}
        float I  = 1.0f + ei, F = 1.0f + ef;
        float Gp = 1.0f + G2;
        float Gms = fmaf(SLOG2E, G2, -SLOG2E);          // s*(G2-1)
        float P   = I * Gp;
        float num = fmaf(F, Gms, cs[r] * P);
        float csn = num * __builtin_amdgcn_rcpf(F * P);
        csn = fminf(fmaxf(csn, -50.0f), 50.0f);
        cs[r] = csn;
        float eo = __builtin_amdgcn_exp2f(acc[3][r]);   // e^{-zo}
        float C2 = __builtin_amdgcn_exp2f(csn);         // e^{2 c'}
        float O  = 1.0f + eo;
        float Cp = 1.0f + C2, Cm = C2 - 1.0f;
        float h  = Cm * __builtin_amdgcn_rcpf(O * Cp);
        if (hout) hout[r] = h;
        hh[r] = (_Float16)h;
    }
}

__global__ void __launch_bounds__(TB, 1)
lstm2_mfma_kernel(const float* __restrict__ x,
                  const float* __restrict__ Wih0, const float* __restrict__ Whh0,
                  const float* __restrict__ bih0, const float* __restrict__ bhh0,
                  const float* __restrict__ Wih1, const float* __restrict__ Whh1,
                  const float* __restrict__ bih1, const float* __restrict__ bhh1,
                  const float* __restrict__ W1,   const float* __restrict__ b1,
                  const float* __restrict__ W2,   const float* __restrict__ b2,
                  float* __restrict__ out)
{
    const int tid  = threadIdx.x;
    const int wl   = tid >> 6;          // wave 0..3: owns hidden slice wl*16..wl*16+15 (both layers)
    const int lane = tid & 63;
    const int n16  = lane & 15;         // MFMA free index / local batch
    const int q    = lane >> 4;         // quad 0..3
    const int j0   = wl * 16 + q * 4;   // this thread's hidden-unit base (4 rows)
    const int b0   = blockIdx.x * NB;

    __shared__ __align__(16) _Float16 SB[SB_HALFS];
    __shared__ __align__(16) float HS[16 * 68 + 16 * 33];

    const float gsc[4] = {-LOG2E, -LOG2E, SLOG2E, -LOG2E};

    // ---------------- per-wave weight fragments: BOTH layers (single fp16) ----------------
    half8 ah0[4][3];        // L0: kt0 = x-side (K=32), kt1..2 = h0-side
    half8 ah1[4][4];        // L1: kt0..1 = h0-side, kt2..3 = h1-side
    float4v biasv0[4], biasv1[4];

    #pragma unroll
    for (int l = 0; l < 4; ++l) {
        const int row = (l * 4 + wl) * 16 + n16;
        const float g = gsc[l];
        float v[8];
        // ---- layer 0 ----
        {
            const float4* p = (const float4*)(Wih0 + row * DIN + q * 8);
            float4 u0 = p[0], u1 = p[1];
            v[0]=g*u0.x; v[1]=g*u0.y; v[2]=g*u0.z; v[3]=g*u0.w;
            v[4]=g*u1.x; v[5]=g*u1.y; v[6]=g*u1.z; v[7]=g*u1.w;
            cvt8(v, ah0[l][0]);
        }
        #pragma unroll
        for (int kt = 1; kt < 3; ++kt) {
            const float4* p = (const float4*)(Whh0 + row * HCELLS + (kt - 1) * 32 + q * 8);
            float4 u0 = p[0], u1 = p[1];
            v[0]=g*u0.x; v[1]=g*u0.y; v[2]=g*u0.z; v[3]=g*u0.w;
            v[4]=g*u1.x; v[5]=g*u1.y; v[6]=g*u1.z; v[7]=g*u1.w;
            cvt8(v, ah0[l][kt]);
        }
        {
            const int r0 = l * 64 + j0;
            float4v bi = *(const float4v*)(bih0 + r0);
            float4v bh = *(const float4v*)(bhh0 + r0);
            biasv0[l] = (bi + bh) * g;
        }
        // ---- layer 1 ----
        #pragma unroll
        for (int kt = 0; kt < 4; ++kt) {
            const float* base = (kt < 2) ? (Wih1 + row * HCELLS + kt * 32)
                                         : (Whh1 + row * HCELLS + (kt - 2) * 32);
            const float4* p = (const float4*)(base + q * 8);
            float4 u0 = p[0], u1 = p[1];
            v[0]=g*u0.x; v[1]=g*u0.y; v[2]=g*u0.z; v[3]=g*u0.w;
            v[4]=g*u1.x; v[5]=g*u1.y; v[6]=g*u1.z; v[7]=g*u1.w;
            cvt8(v, ah1[l][kt]);
        }
        {
            const int r0 = l * 64 + j0;
            float4v bi = *(const float4v*)(bih1 + r0);
            float4v bh = *(const float4v*)(bhh1 + r0);
            biasv1[l] = (bi + bh) * g;
        }
    }

    // ---------------- zero LDS h buffers ----------------
    for (int i = tid; i < SB_HALFS / 2; i += TB) ((int*)SB)[i] = 0;

    // x B-fragment pointer: lane (n16, q) reads x[b0+n16][t][q*8 .. q*8+7] directly
    // (same fp32->fp16 conversion as the old LDS-staged path => identical numerics;
    //  all 4 waves read the same 16 cache lines -> L1 absorbs the redundancy)
    const float* xq = x + ((size_t)(b0 + n16) * T) * DIN + q * 8;
    float4 xn0 = *(const float4*)xq;
    float4 xn1 = *(const float4*)(xq + 4);
    xq += DIN;

    __syncthreads();

    float cs0[4] = {0, 0, 0, 0};
    float cs1[4] = {0, 0, 0, 0};
    float hlast[4];

    // ---------------- region 0: L0(0) only (h0(-1)=0 => x + bias) ----------------
    {
        float4 xc0 = xn0, xc1 = xn1;
        xn0 = *(const float4*)xq; xn1 = *(const float4*)(xq + 4); xq += DIN;  // prefetch x(1)
        half8 bhx;
        bhx[0]=(_Float16)xc0.x; bhx[1]=(_Float16)xc0.y; bhx[2]=(_Float16)xc0.z; bhx[3]=(_Float16)xc0.w;
        bhx[4]=(_Float16)xc1.x; bhx[5]=(_Float16)xc1.y; bhx[6]=(_Float16)xc1.z; bhx[7]=(_Float16)xc1.w;
        float4v acc0[4];
        #pragma unroll
        for (int l = 0; l < 4; ++l)
            acc0[l] = __builtin_amdgcn_mfma_f32_16x16x32_f16(ah0[l][0], bhx, biasv0[l], 0, 0, 0);
        half4v hh0;
        cell_update(acc0, cs0, hh0, nullptr);
        *(half4v*)&SB[H0H_OFF + hidx(1, n16, j0)] = hh0;   // h0(0) -> slot 1
        __syncthreads();
    }

    // ---------------- main loop: region t computes L0(t) and L1(t-1) ----------------
    // h0(tau) lives in slot (tau+1)&1 ; h1(tau) lives in slot tau&1
    #pragma unroll 2
    for (int t = 1; t < T; ++t) {
        const int pr = t & 1, pw = pr ^ 1;

        // x(t) from regs; prefetch x(t+1) (in flight across this region's compute)
        float4 xc0 = xn0, xc1 = xn1;
        if (t + 1 < T) { xn0 = *(const float4*)xq; xn1 = *(const float4*)(xq + 4); xq += DIN; }

        half8 bhx;
        bhx[0]=(_Float16)xc0.x; bhx[1]=(_Float16)xc0.y; bhx[2]=(_Float16)xc0.z; bhx[3]=(_Float16)xc0.w;
        bhx[4]=(_Float16)xc1.x; bhx[5]=(_Float16)xc1.y; bhx[6]=(_Float16)xc1.z; bhx[7]=(_Float16)xc1.w;

        // shared reads: h0(t-1) feeds BOTH L0 and L1; h1(t-2) feeds L1
        half8 bh0a = *(const half8*)&SB[H0H_OFF + hidx(pr, n16, q * 8)];
        half8 bh0b = *(const half8*)&SB[H0H_OFF + hidx(pr, n16, 32 + q * 8)];
        half8 bh1a = *(const half8*)&SB[H1H_OFF + hidx(pw, n16, q * 8)];
        half8 bh1b = *(const half8*)&SB[H1H_OFF + hidx(pw, n16, 32 + q * 8)];

        float4v acc0[4], acc1[4];
        #pragma unroll
        for (int l = 0; l < 4; ++l) {
            acc0[l] = __builtin_amdgcn_mfma_f32_16x16x32_f16(ah0[l][0], bhx,  biasv0[l], 0, 0, 0);
            acc1[l] = __builtin_amdgcn_mfma_f32_16x16x32_f16(ah1[l][0], bh0a, biasv1[l], 0, 0, 0);
        }
        #pragma unroll
        for (int l = 0; l < 4; ++l) {
            acc0[l] = __builtin_amdgcn_mfma_f32_16x16x32_f16(ah0[l][1], bh0a, acc0[l], 0, 0, 0);
            acc0[l] = __builtin_amdgcn_mfma_f32_16x16x32_f16(ah0[l][2], bh0b, acc0[l], 0, 0, 0);
            acc1[l] = __builtin_amdgcn_mfma_f32_16x16x32_f16(ah1[l][1], bh0b, acc1[l], 0, 0, 0);
            acc1[l] = __builtin_amdgcn_mfma_f32_16x16x32_f16(ah1[l][2], bh1a, acc1[l], 0, 0, 0);
            acc1[l] = __builtin_amdgcn_mfma_f32_16x16x32_f16(ah1[l][3], bh1b, acc1[l], 0, 0, 0);
        }

        // two independent cell updates -> 8-row ILP for the trans chains
        half4v hh0, hh1;
        cell_update(acc0, cs0, hh0, nullptr);
        cell_update(acc1, cs1, hh1, nullptr);
        *(half4v*)&SB[H0H_OFF + hidx(pw, n16, j0)] = hh0;   // h0(t)   -> slot pw
        *(half4v*)&SB[H1H_OFF + hidx(pr, n16, j0)] = hh1;   // h1(t-1) -> slot pr
        __syncthreads();
    }

    // ---------------- epilogue: L1(T-1) ----------------
    // h0(T-1) in slot 0 ; h1(T-2) in slot 1   (T even)
    float* h1f = HS;             // [16][68]
    float* hid = HS + 16 * 68;   // [16][33]
    {
        half8 bh0a = *(const half8*)&SB[H0H_OFF + hidx(0, n16, q * 8)];
        half8 bh0b = *(const half8*)&SB[H0H_OFF + hidx(0, n16, 32 + q * 8)];
        half8 bh1a = *(const half8*)&SB[H1H_OFF + hidx(1, n16, q * 8)];
        half8 bh1b = *(const half8*)&SB[H1H_OFF + hidx(1, n16, 32 + q * 8)];
        float4v acc[4];
        #pragma unroll
        for (int l = 0; l < 4; ++l) {
            acc[l] = __builtin_amdgcn_mfma_f32_16x16x32_f16(ah1[l][0], bh0a, biasv1[l], 0, 0, 0);
            acc[l] = __builtin_amdgcn_mfma_f32_16x16x32_f16(ah1[l][1], bh0b, acc[l], 0, 0, 0);
            acc[l] = __builtin_amdgcn_mfma_f32_16x16x32_f16(ah1[l][2], bh1a, acc[l], 0, 0, 0);
            acc[l] = __builtin_amdgcn_mfma_f32_16x16x32_f16(ah1[l][3], bh1b, acc[l], 0, 0, 0);
        }
        half4v hh;
        cell_update(acc, cs1, hh, hlast);
        #pragma unroll
        for (int r = 0; r < 4; ++r) h1f[n16 * 68 + j0 + r] = hlast[r];
    }
    __syncthreads();

    // ---------------- head: relu(h1 @ W1^T + b1) @ W2^T + b2 ----------------
    {
        const int n2 = tid >> 4, m = tid & 15;
        float s0 = b1[m], s1 = b1[m + 16];
        const float* w0p = W1 + m * HCELLS;
        const float* w1p = W1 + (m + 16) * HCELLS;
        #pragma unroll
        for (int j = 0; j < HCELLS; ++j) {
            float hv = h1f[n2 * 68 + j];
            s0 = fmaf(w0p[j], hv, s0);
            s1 = fmaf(w1p[j], hv, s1);
        }
        hid[n2 * 33 + m]      = fmaxf(s0, 0.0f);
        hid[n2 * 33 + m + 16] = fmaxf(s1, 0.0f);
    }
    __syncthreads();

    if (tid < NB) {
        float s = b2[0];
        #pragma unroll
        for (int m = 0; m < 32; ++m) s = fmaf(W2[m], hid[tid * 33 + m], s);
        out[b0 + tid] = s;
    }
}

extern "C" void kernel_launch(void* const* d_in, const int* in_sizes, int n_in,
                              void* d_out, int out_size, void* d_ws, size_t ws_size,
                              hipStream_t stream) {
    const float* x    = (const float*)d_in[0];
    const float* Wih0 = (const float*)d_in[1];
    const float* Whh0 = (const float*)d_in[2];
    const float* bih0 = (const float*)d_in[3];
    const float* bhh0 = (const float*)d_in[4];
    const float* Wih1 = (const float*)d_in[5];
    const float* Whh1 = (const float*)d_in[6];
    const float* bih1 = (const float*)d_in[7];
    const float* bhh1 = (const float*)d_in[8];
    const float* W1   = (const float*)d_in[9];
    const float* b1   = (const float*)d_in[10];
    const float* W2   = (const float*)d_in[11];
    const float* b2   = (const float*)d_in[12];
    float* out = (float*)d_out;

    hipLaunchKernelGGL(lstm2_mfma_kernel, dim3(GRID), dim3(TB), 0, stream,
                       x, Wih0, Whh0, bih0, bhh0, Wih1, Whh1, bih1, bhh1,
                       W1, b1, W2, b2, out);
}

// Round 2
// 454.953 us; speedup vs baseline: 1.3449x; 1.3449x over previous
//
#include <hip/hip_runtime.h>

#define T       512
#define DIN     32
#define HCELLS  64
#define NB      16      // batch elems per block (MFMA N dim)
#define TB      512     // 8 waves: group A = waves 0-3 (layer 0), group B = waves 4-7 (layer 1)
#define GRID    64      // 1024 / NB

typedef _Float16 half8  __attribute__((ext_vector_type(8)));
typedef _Float16 half4v __attribute__((ext_vector_type(4)));
typedef float    float4v __attribute__((ext_vector_type(4)));

// LDS fp16 double-buffered h state only (x lives in per-wave registers now).
#define STRH    72      // h rows: 64 + 8 pad (halfs)
#define H0H_OFF 0                       // [2][16][STRH]
#define H1H_OFF (2*16*STRH)
#define SB_HALFS (H1H_OFF + 2*16*STRH)

#define LOG2E   1.44269504f
#define SLOG2E  2.88539008f     // 2*log2(e); cell state kept as cs = SLOG2E * c

// Raw barrier: orders LDS (lgkmcnt) but does NOT drain vmcnt -> global x
// prefetch loads stay in flight across the barrier (use-site vmcnt wait is
// one full region later, covering ~900cy HBM latency).
#define BARRIER() asm volatile("s_waitcnt lgkmcnt(0)\n\ts_barrier" ::: "memory")

__device__ __forceinline__ int hidx(int p, int n, int k) { return (p * 16 + n) * STRH + k; }

__device__ __forceinline__ void cvt8(const float* v, half8& hi) {
    #pragma unroll
    for (int e = 0; e < 8; ++e) hi[e] = (_Float16)v[e];
}

// Scaled-domain LSTM cell update (gate scales folded into weights):
//   acc[0]=-log2e*zi, acc[1]=-log2e*zf, acc[2]=2log2e*zg, acc[3]=-log2e*zo ; cs = 2log2e*c
__device__ __forceinline__ void cell_update(const float4v acc[4], float* cs,
                                            half4v& hh, float* hout)
{
    #pragma unroll
    for (int r = 0; r < 4; ++r) {
        float ei = __builtin_amdgcn_exp2f(acc[0][r]);   // e^{-zi}
        float ef = __builtin_amdgcn_exp2f(acc[1][r]);   // e^{-zf}
        float G2 = __builtin_amdgcn_exp2f(acc[2][r]);   // e^{2 zg}
        float I  = 1.0f + ei, F = 1.0f + ef;
        float Gp = 1.0f + G2;
        float Gms = fmaf(SLOG2E, G2, -SLOG2E);          // s*(G2-1)
        float P   = I * Gp;
        float num = fmaf(F, Gms, cs[r] * P);
        float csn = num * __builtin_amdgcn_rcpf(F * P);
        csn = fminf(fmaxf(csn, -50.0f), 50.0f);
        cs[r] = csn;
        float eo = __builtin_amdgcn_exp2f(acc[3][r]);   // e^{-zo}
        float C2 = __builtin_amdgcn_exp2f(csn);         // e^{2 c'}
        float O  = 1.0f + eo;
        float Cp = 1.0f + C2, Cm = C2 - 1.0f;
        float h  = Cm * __builtin_amdgcn_rcpf(O * Cp);
        if (hout) hout[r] = h;
        hh[r] = (_Float16)h;
    }
}

__global__ void __launch_bounds__(TB, 2)
lstm2_mfma_kernel(const float* __restrict__ x,
                  const float* __restrict__ Wih0, const float* __restrict__ Whh0,
                  const float* __restrict__ bih0, const float* __restrict__ bhh0,
                  const float* __restrict__ Wih1, const float* __restrict__ Whh1,
                  const float* __restrict__ bih1, const float* __restrict__ bhh1,
                  const float* __restrict__ W1,   const float* __restrict__ b1,
                  const float* __restrict__ W2,   const float* __restrict__ b2,
                  float* __restrict__ out)
{
    const int tid  = threadIdx.x;
    const int wid  = tid >> 6;
    const int grp  = wid >> 2;          // 0 = layer-0 group, 1 = layer-1 group
    const int wl   = wid & 3;           // local wave in group
    const int lane = tid & 63;
    const int n16  = lane & 15;         // MFMA free index / local batch
    const int q    = lane >> 4;         // quad 0..3
    const int j0   = wl * 16 + q * 4;   // this thread's hidden-unit base (4 rows)
    const int b0   = blockIdx.x * NB;

    __shared__ __align__(16) _Float16 SB[SB_HALFS];
    __shared__ __align__(16) float HS[16 * 68 + 16 * 33];

    const float gsc[4] = {-LOG2E, -LOG2E, SLOG2E, -LOG2E};

    // ---------------- per-group weight fragments (single fp16) ----------------
    half8 ah[4][4];
    float4v biasv[4];

    #pragma unroll
    for (int l = 0; l < 4; ++l) {
        const int row = (l * 4 + wl) * 16 + n16;
        const float g = gsc[l];
        float v[8];
        if (grp == 0) {
            {
                const float4* p = (const float4*)(Wih0 + row * DIN + q * 8);
                float4 u0 = p[0], u1 = p[1];
                v[0]=g*u0.x; v[1]=g*u0.y; v[2]=g*u0.z; v[3]=g*u0.w;
                v[4]=g*u1.x; v[5]=g*u1.y; v[6]=g*u1.z; v[7]=g*u1.w;
                cvt8(v, ah[l][0]);
            }
            #pragma unroll
            for (int kt = 1; kt < 3; ++kt) {
                const float4* p = (const float4*)(Whh0 + row * HCELLS + (kt - 1) * 32 + q * 8);
                float4 u0 = p[0], u1 = p[1];
                v[0]=g*u0.x; v[1]=g*u0.y; v[2]=g*u0.z; v[3]=g*u0.w;
                v[4]=g*u1.x; v[5]=g*u1.y; v[6]=g*u1.z; v[7]=g*u1.w;
                cvt8(v, ah[l][kt]);
            }
            const int r0 = l * 64 + j0;
            float4v bi = *(const float4v*)(bih0 + r0);
            float4v bh = *(const float4v*)(bhh0 + r0);
            biasv[l] = (bi + bh) * g;
        } else {
            #pragma unroll
            for (int kt = 0; kt < 4; ++kt) {
                const float* base = (kt < 2) ? (Wih1 + row * HCELLS + kt * 32)
                                             : (Whh1 + row * HCELLS + (kt - 2) * 32);
                const float4* p = (const float4*)(base + q * 8);
                float4 u0 = p[0], u1 = p[1];
                v[0]=g*u0.x; v[1]=g*u0.y; v[2]=g*u0.z; v[3]=g*u0.w;
                v[4]=g*u1.x; v[5]=g*u1.y; v[6]=g*u1.z; v[7]=g*u1.w;
                cvt8(v, ah[l][kt]);
            }
            const int r0 = l * 64 + j0;
            float4v bi = *(const float4v*)(bih1 + r0);
            float4v bh = *(const float4v*)(bhh1 + r0);
            biasv[l] = (bi + bh) * g;
        }
    }

    // ---------------- zero LDS h buffers ----------------
    for (int i = tid; i < SB_HALFS / 2; i += TB) ((int*)SB)[i] = 0;

    // x B-fragment: lane (n16, q) of each group-A wave reads
    // x[b0+n16][t][q*8 .. q*8+7] directly (fp32->fp16 at use: identical numerics
    // to the old LDS-staged path; 4x wave redundancy absorbed by L1).
    const float* xq = nullptr;
    float4 xn0, xn1;
    if (grp == 0) {
        xq = x + ((size_t)(b0 + n16) * T) * DIN + q * 8;
        xn0 = *(const float4*)xq;
        xn1 = *(const float4*)(xq + 4);
        xq += DIN;
    }

    __syncthreads();

    float cs[4] = {0, 0, 0, 0};
    float hlast[4];

    // ---------------- pipelined time loop: ONE raw barrier per region ----------------
    // region t: A computes L0(t); B computes L1(t-1) (t>=1)
    // h0(tau) lives in slot (tau+1)&1 ; h1(tau) lives in slot tau&1
    #pragma unroll 2
    for (int t = 0; t < T; ++t) {
        const int pr = t & 1, pw = pr ^ 1;

        if (grp == 0) {
            // x(t) from regs; prefetch x(t+1) (stays in flight across the raw barrier)
            float4 xc0 = xn0, xc1 = xn1;
            if (t + 1 < T) { xn0 = *(const float4*)xq; xn1 = *(const float4*)(xq + 4); xq += DIN; }

            half8 bhx;
            bhx[0]=(_Float16)xc0.x; bhx[1]=(_Float16)xc0.y; bhx[2]=(_Float16)xc0.z; bhx[3]=(_Float16)xc0.w;
            bhx[4]=(_Float16)xc1.x; bhx[5]=(_Float16)xc1.y; bhx[6]=(_Float16)xc1.z; bhx[7]=(_Float16)xc1.w;

            float4v acc[4];
            #pragma unroll
            for (int l = 0; l < 4; ++l)
                acc[l] = __builtin_amdgcn_mfma_f32_16x16x32_f16(ah[l][0], bhx, biasv[l], 0, 0, 0);
            // kt=1,2: h0(t-1) @ H0[pr]   (slot 0 pre-zeroed => h0(-1)=0 at t=0)
            #pragma unroll
            for (int kt = 1; kt < 3; ++kt) {
                half8 bh = *(const half8*)&SB[H0H_OFF + hidx(pr, n16, (kt - 1) * 32 + q * 8)];
                #pragma unroll
                for (int l = 0; l < 4; ++l)
                    acc[l] = __builtin_amdgcn_mfma_f32_16x16x32_f16(ah[l][kt], bh, acc[l], 0, 0, 0);
            }
            half4v hh;
            cell_update(acc, cs, hh, nullptr);
            *(half4v*)&SB[H0H_OFF + hidx(pw, n16, j0)] = hh;   // h0(t) -> slot pw
        } else if (t > 0) {
            // L1(t-1): h0(t-1) @ H0[pr], h1(t-2) @ H1[pw]
            float4v acc[4];
            #pragma unroll
            for (int l = 0; l < 4; ++l) acc[l] = biasv[l];
            #pragma unroll
            for (int kt = 0; kt < 4; ++kt) {
                half8 bh = (kt < 2)
                    ? *(const half8*)&SB[H0H_OFF + hidx(pr, n16, kt * 32 + q * 8)]
                    : *(const half8*)&SB[H1H_OFF + hidx(pw, n16, (kt - 2) * 32 + q * 8)];
                #pragma unroll
                for (int l = 0; l < 4; ++l)
                    acc[l] = __builtin_amdgcn_mfma_f32_16x16x32_f16(ah[l][kt], bh, acc[l], 0, 0, 0);
            }
            half4v hh;
            cell_update(acc, cs, hh, nullptr);
            *(half4v*)&SB[H1H_OFF + hidx(pr, n16, j0)] = hh;   // h1(t-1) -> slot pr
        }
        BARRIER();
    }

    // ---------------- epilogue: B computes L1(T-1) ----------------
    // h0(T-1) in slot 0 ; h1(T-2) in slot 1   (T even)
    float* h1f = HS;             // [16][68]
    float* hid = HS + 16 * 68;   // [16][33]
    if (grp == 1) {
        float4v acc[4];
        #pragma unroll
        for (int l = 0; l < 4; ++l) acc[l] = biasv[l];
        #pragma unroll
        for (int kt = 0; kt < 4; ++kt) {
            half8 bh = (kt < 2)
                ? *(const half8*)&SB[H0H_OFF + hidx(0, n16, kt * 32 + q * 8)]
                : *(const half8*)&SB[H1H_OFF + hidx(1, n16, (kt - 2) * 32 + q * 8)];
            #pragma unroll
            for (int l = 0; l < 4; ++l)
                acc[l] = __builtin_amdgcn_mfma_f32_16x16x32_f16(ah[l][kt], bh, acc[l], 0, 0, 0);
        }
        half4v hh;
        cell_update(acc, cs, hh, hlast);
        *(float4*)&h1f[n16 * 68 + j0] = *(const float4*)hlast;
    }
    __syncthreads();

    // ---------------- head: relu(h1 @ W1^T + b1) @ W2^T + b2 ----------------
    if (tid < 256) {
        const int n2 = tid >> 4, m = tid & 15;
        float s0 = b1[m], s1 = b1[m + 16];
        const float* w0p = W1 + m * HCELLS;
        const float* w1p = W1 + (m + 16) * HCELLS;
        #pragma unroll
        for (int j = 0; j < HCELLS; ++j) {
            float hv = h1f[n2 * 68 + j];
            s0 = fmaf(w0p[j], hv, s0);
            s1 = fmaf(w1p[j], hv, s1);
        }
        hid[n2 * 33 + m]      = fmaxf(s0, 0.0f);
        hid[n2 * 33 + m + 16] = fmaxf(s1, 0.0f);
    }
    __syncthreads();

    if (tid < NB) {
        float s = b2[0];
        #pragma unroll
        for (int m = 0; m < 32; ++m) s = fmaf(W2[m], hid[tid * 33 + m], s);
        out[b0 + tid] = s;
    }
}

extern "C" void kernel_launch(void* const* d_in, const int* in_sizes, int n_in,
                              void* d_out, int out_size, void* d_ws, size_t ws_size,
                              hipStream_t stream) {
    const float* x    = (const float*)d_in[0];
    const float* Wih0 = (const float*)d_in[1];
    const float* Whh0 = (const float*)d_in[2];
    const float* bih0 = (const float*)d_in[3];
    const float* bhh0 = (const float*)d_in[4];
    const float* Wih1 = (const float*)d_in[5];
    const float* Whh1 = (const float*)d_in[6];
    const float* bih1 = (const float*)d_in[7];
    const float* bhh1 = (const float*)d_in[8];
    const float* W1   = (const float*)d_in[9];
    const float* b1   = (const float*)d_in[10];
    const float* W2   = (const float*)d_in[11];
    const float* b2   = (const float*)d_in[12];
    float* out = (float*)d_out;

    hipLaunchKernelGGL(lstm2_mfma_kernel, dim3(GRID), dim3(TB), 0, stream,
                       x, Wih0, Whh0, bih0, bhh0, Wih1, Whh1, bih1, bhh1,
                       W1, b1, W2, b2, out);
}